// Round 1
// baseline (565.248 us; speedup 1.0000x reference)
//
#include <hip/hip_runtime.h>
#include <hip/hip_bf16.h>
#include <stdint.h>

#define B_   2
#define N_   2048
#define DIN  2048
#define DOUT 2048
#define H_   32
#define G_   8
#define HD_  64
#define M_   (B_*N_)   // 4096

using short8 = __attribute__((ext_vector_type(8))) short;
using f32x4  = __attribute__((ext_vector_type(4))) float;

__device__ __forceinline__ unsigned short f2bf(float f) {
  unsigned int u = __float_as_uint(f);
  unsigned int r = u + 0x7FFFu + ((u >> 16) & 1u);
  return (unsigned short)(r >> 16);
}
__device__ __forceinline__ float bf2f(unsigned short h) {
  return __uint_as_float(((unsigned int)h) << 16);
}

// ---------------- elementwise f32 -> bf16 (4 elems/thread) ----------------
__global__ void k_cvt(const float* __restrict__ in, unsigned short* __restrict__ out, int n4) {
  int i = blockIdx.x * 256 + threadIdx.x;
  if (i >= n4) return;
  float4 v = reinterpret_cast<const float4*>(in)[i];
  uint2 o;
  o.x = (unsigned int)f2bf(v.x) | ((unsigned int)f2bf(v.y) << 16);
  o.y = (unsigned int)f2bf(v.z) | ((unsigned int)f2bf(v.w) << 16);
  reinterpret_cast<uint2*>(out)[i] = o;
}

// ---------------- transpose + convert: W (R x C) f32 -> Wt (C x R) bf16 ----------------
__global__ void k_transpose(const float* __restrict__ W, unsigned short* __restrict__ Wt,
                            int R, int C) {
  __shared__ float tile[32][33];
  int c0 = blockIdx.x * 32, r0 = blockIdx.y * 32;
  int tx = threadIdx.x, ty = threadIdx.y;  // (32,8)
  #pragma unroll
  for (int j = 0; j < 4; ++j)
    tile[ty + j*8][tx] = W[(size_t)(r0 + ty + j*8) * C + c0 + tx];
  __syncthreads();
  #pragma unroll
  for (int j = 0; j < 4; ++j)
    Wt[(size_t)(c0 + ty + j*8) * R + r0 + tx] = f2bf(tile[tx][ty + j*8]);
}

// ---------------- in-place RoPE on bf16 (thread owns the (d, d+32) pair) ----------------
__global__ void k_rope(unsigned short* __restrict__ X, const float* __restrict__ cosT,
                       const float* __restrict__ sinT, int nheads, int rowStride) {
  int idx = blockIdx.x * 256 + threadIdx.x;
  int dp  = idx & 31;
  int hh  = (idx >> 5) % nheads;
  int row = idx / (32 * nheads);
  if (row >= M_) return;
  int n = row & (N_ - 1);
  float c = cosT[n*HD_ + dp], s = sinT[n*HD_ + dp];
  unsigned short* p = X + (size_t)row * rowStride + hh*HD_ + dp;
  float x1 = bf2f(p[0]), x2 = bf2f(p[32]);
  p[0]  = f2bf(x1*c - x2*s);
  p[32] = f2bf(x2*c + x1*s);
}

// ---------------- bf16 GEMM, B given transposed (Bt: N x K row-major) ----------------
// 128x128 tile, BK=32, 4 waves (2x2), global_load_lds staging with XOR chunk swizzle.
template <typename OUT>
__global__ void __launch_bounds__(256)
k_gemm_bt(const unsigned short* __restrict__ A, const unsigned short* __restrict__ Bt,
          OUT* __restrict__ C, int M, int N, int K) {
  __shared__ unsigned short As[128 * 32];
  __shared__ unsigned short Bs[128 * 32];
  const int tid  = threadIdx.x;
  const int wid  = tid >> 6, l = tid & 63;
  const int lrow = l & 15,  lk = l >> 4;
  const int wm = wid >> 1,  wn = wid & 1;
  const int rowA0 = blockIdx.y * 128, rowB0 = blockIdx.x * 128;

  f32x4 acc[4][4];
  #pragma unroll
  for (int m = 0; m < 4; ++m)
    #pragma unroll
    for (int n = 0; n < 4; ++n)
      #pragma unroll
      for (int r = 0; r < 4; ++r) acc[m][n][r] = 0.f;

  // staging slots: slot = issue*4096 + wid*1024 + l*16 bytes; LDS linear, source pre-swizzled
  int srow[2], scol[2];
  #pragma unroll
  for (int issue = 0; issue < 2; ++issue) {
    int slot = issue*4096 + wid*1024 + l*16;
    int row  = slot >> 6;          // 0..127
    int cp   = (slot >> 4) & 3;    // 16B chunk within row
    int sw   = (row & 3) ^ ((row >> 2) & 3);
    srow[issue] = row;
    scol[issue] = (cp ^ sw) * 8;   // element offset of the global chunk this slot holds
  }
  const int swr    = (lrow & 3) ^ ((lrow >> 2) & 3);
  const int rchunk = (lk ^ swr) * 8;   // swizzled read chunk (elements)

  for (int kt = 0; kt < K; kt += 32) {
    __syncthreads();   // previous compute done before overwriting LDS
    #pragma unroll
    for (int issue = 0; issue < 2; ++issue) {
      const unsigned short* ga = A  + (size_t)(rowA0 + srow[issue]) * K + kt + scol[issue];
      const unsigned short* gb = Bt + (size_t)(rowB0 + srow[issue]) * K + kt + scol[issue];
      __builtin_amdgcn_global_load_lds(
          (const __attribute__((address_space(1))) unsigned int*)ga,
          (__attribute__((address_space(3))) unsigned int*)((char*)As + issue*4096 + wid*1024),
          16, 0, 0);
      __builtin_amdgcn_global_load_lds(
          (const __attribute__((address_space(1))) unsigned int*)gb,
          (__attribute__((address_space(3))) unsigned int*)((char*)Bs + issue*4096 + wid*1024),
          16, 0, 0);
    }
    asm volatile("s_waitcnt vmcnt(0)" ::: "memory");
    __syncthreads();

    short8 av[4], bv[4];
    #pragma unroll
    for (int m = 0; m < 4; ++m)
      av[m] = *reinterpret_cast<const short8*>(&As[(wm*64 + m*16 + lrow)*32 + rchunk]);
    #pragma unroll
    for (int n = 0; n < 4; ++n)
      bv[n] = *reinterpret_cast<const short8*>(&Bs[(wn*64 + n*16 + lrow)*32 + rchunk]);
    #pragma unroll
    for (int m = 0; m < 4; ++m)
      #pragma unroll
      for (int n = 0; n < 4; ++n)
        acc[m][n] = __builtin_amdgcn_mfma_f32_16x16x32_bf16(av[m], bv[n], acc[m][n], 0, 0, 0);
  }

  #pragma unroll
  for (int m = 0; m < 4; ++m) {
    int row0 = rowA0 + wm*64 + m*16 + lk*4;
    #pragma unroll
    for (int n = 0; n < 4; ++n) {
      int col = rowB0 + wn*64 + n*16 + lrow;
      #pragma unroll
      for (int r = 0; r < 4; ++r) {
        float v = acc[m][n][r];
        if constexpr (sizeof(OUT) == 2) C[(size_t)(row0 + r) * N + col] = (OUT)f2bf(v);
        else                            C[(size_t)(row0 + r) * N + col] = v;
      }
    }
  }
}

// ---------------- causal GQA flash attention ----------------
// grid (N/64, H, B), 256 threads = 4 waves; wave owns 16 q-rows.
// Q frags in regs; K frags straight from global (L2-resident); V^T staged in LDS (swizzled);
// P re-laid-out through a per-wave LDS buffer.
__global__ void __launch_bounds__(256)
k_attn(const unsigned short* __restrict__ Q, const unsigned short* __restrict__ KV,
       unsigned short* __restrict__ ctx) {
  const int qt = blockIdx.x, h = blockIdx.y, b = blockIdx.z;
  const int g = h >> 2;          // R = 4 query heads per KV group
  const int tid = threadIdx.x, wid = tid >> 6, l = tid & 63;
  const int lrow = l & 15, lk = l >> 4;
  const int qbase = qt*64 + wid*16;

  __shared__ unsigned short Vt[64 * 32];          // [d][key-chunk swizzled]
  __shared__ unsigned short Plds[4][16][32];      // per wave: [q-local][key-local]

  const unsigned short* qp = Q + (size_t)(b*N_ + qbase + lrow) * DOUT + h*HD_;
  short8 aq0 = *reinterpret_cast<const short8*>(qp + lk*8);
  short8 aq1 = *reinterpret_cast<const short8*>(qp + 32 + lk*8);

  float m_run[4], l_run[4];
  f32x4 acc[4];
  #pragma unroll
  for (int r = 0; r < 4; ++r) { m_run[r] = -__builtin_inff(); l_run[r] = 0.f; }
  #pragma unroll
  for (int dt = 0; dt < 4; ++dt)
    #pragma unroll
    for (int r = 0; r < 4; ++r) acc[dt][r] = 0.f;

  const int vkey = tid >> 3;   // 0..31
  const int vdc  = tid & 7;    // 0..7
  const int nkb  = qt*2 + 2;   // 32-key blocks covering keys <= qbase+63

  for (int kb = 0; kb < nkb; ++kb) {
    __syncthreads();   // prior PV reads of Vt complete
    {
      int key = kb*32 + vkey;
      const unsigned short* vp = KV + (size_t)(b*N_ + key) * 1024 + 512 + g*HD_ + vdc*8;
      short8 vv = *reinterpret_cast<const short8*>(vp);
      #pragma unroll
      for (int i = 0; i < 8; ++i) {
        int d  = vdc*8 + i;
        int sw = (d & 3) ^ ((d >> 2) & 3);
        int cs = (vkey >> 3) ^ sw;
        Vt[d*32 + cs*8 + (vkey & 7)] = (unsigned short)vv[i];
      }
    }
    __syncthreads();

    // ---- S = Q K^T for two 16-key tiles ----
    f32x4 s0, s1;
    {
      const unsigned short* kp = KV + (size_t)(b*N_ + kb*32 + lrow) * 1024 + g*HD_;
      short8 bk0 = *reinterpret_cast<const short8*>(kp + lk*8);
      short8 bk1 = *reinterpret_cast<const short8*>(kp + 32 + lk*8);
      f32x4 z;
      #pragma unroll
      for (int r = 0; r < 4; ++r) z[r] = 0.f;
      z  = __builtin_amdgcn_mfma_f32_16x16x32_bf16(aq0, bk0, z, 0, 0, 0);
      s0 = __builtin_amdgcn_mfma_f32_16x16x32_bf16(aq1, bk1, z, 0, 0, 0);
      kp += (size_t)16 * 1024;
      bk0 = *reinterpret_cast<const short8*>(kp + lk*8);
      bk1 = *reinterpret_cast<const short8*>(kp + 32 + lk*8);
      #pragma unroll
      for (int r = 0; r < 4; ++r) z[r] = 0.f;
      z  = __builtin_amdgcn_mfma_f32_16x16x32_bf16(aq0, bk0, z, 0, 0, 0);
      s1 = __builtin_amdgcn_mfma_f32_16x16x32_bf16(aq1, bk1, z, 0, 0, 0);
    }

    // ---- causal mask + scale + online softmax ----
    float sv0[4], sv1[4], mt[4];
    #pragma unroll
    for (int r = 0; r < 4; ++r) {
      int q  = qbase + lk*4 + r;
      int k0 = kb*32 + lrow;
      sv0[r] = (k0      <= q) ? s0[r]*0.125f : -__builtin_inff();
      sv1[r] = (k0 + 16 <= q) ? s1[r]*0.125f : -__builtin_inff();
      mt[r]  = fmaxf(sv0[r], sv1[r]);
    }
    #pragma unroll
    for (int r = 0; r < 4; ++r)
      #pragma unroll
      for (int off = 1; off < 16; off <<= 1)
        mt[r] = fmaxf(mt[r], __shfl_xor(mt[r], off));

    float fr[4], psum[4];
    #pragma unroll
    for (int r = 0; r < 4; ++r) {
      float nm = fmaxf(m_run[r], mt[r]);
      fr[r] = __expf(m_run[r] - nm);
      m_run[r] = nm;
      float p0 = __expf(sv0[r] - nm);
      float p1 = __expf(sv1[r] - nm);
      psum[r] = p0 + p1;
      Plds[wid][lk*4 + r][lrow]      = f2bf(p0);
      Plds[wid][lk*4 + r][16 + lrow] = f2bf(p1);
    }
    #pragma unroll
    for (int r = 0; r < 4; ++r) {
      #pragma unroll
      for (int off = 1; off < 16; off <<= 1)
        psum[r] += __shfl_xor(psum[r], off);
      l_run[r] = l_run[r]*fr[r] + psum[r];
    }
    #pragma unroll
    for (int dt = 0; dt < 4; ++dt)
      #pragma unroll
      for (int r = 0; r < 4; ++r) acc[dt][r] *= fr[r];

    // ---- PV ----
    short8 pf = *reinterpret_cast<const short8*>(&Plds[wid][lrow][lk*8]);
    #pragma unroll
    for (int dt = 0; dt < 4; ++dt) {
      int d  = dt*16 + lrow;
      int sw = (d & 3) ^ ((d >> 2) & 3);
      int cs = lk ^ sw;
      short8 vf = *reinterpret_cast<const short8*>(&Vt[d*32 + cs*8]);
      acc[dt] = __builtin_amdgcn_mfma_f32_16x16x32_bf16(pf, vf, acc[dt], 0, 0, 0);
    }
  }

  #pragma unroll
  for (int dt = 0; dt < 4; ++dt)
    #pragma unroll
    for (int r = 0; r < 4; ++r) {
      int q = qbase + lk*4 + r;
      float ov = acc[dt][r] / l_run[r];
      ctx[(size_t)(b*N_ + q) * DOUT + h*HD_ + dt*16 + lrow] = f2bf(ov);
    }
}

// ---------------- launcher ----------------
extern "C" void kernel_launch(void* const* d_in, const int* in_sizes, int n_in,
                              void* d_out, int out_size, void* d_ws, size_t ws_size,
                              hipStream_t stream) {
  const float* x    = (const float*)d_in[0];
  const float* cosT = (const float*)d_in[1];
  const float* sinT = (const float*)d_in[2];
  const float* Wq   = (const float*)d_in[4];
  const float* Wk   = (const float*)d_in[5];
  const float* Wv   = (const float*)d_in[6];
  const float* Wo   = (const float*)d_in[7];
  float* out = (float*)d_out;

  char* ws = (char*)d_ws;
  unsigned short* xb    = (unsigned short*)(ws);               // 16,777,216 B (reused as ctxb)
  unsigned short* ctxb  = xb;
  unsigned short* Wq_t  = (unsigned short*)(ws + 16777216);    //  8,388,608 B
  unsigned short* Wkv_t = (unsigned short*)(ws + 25165824);    //  4,194,304 B
  unsigned short* Wo_t  = (unsigned short*)(ws + 29360128);    //  8,388,608 B
  unsigned short* Qb    = (unsigned short*)(ws + 37748736);    // 16,777,216 B
  unsigned short* KVb   = (unsigned short*)(ws + 54525952);    //  8,388,608 B
  // total 62,914,560 B

  k_cvt<<<dim3(M_*DIN/4/256), dim3(256), 0, stream>>>(x, xb, M_*DIN/4);

  dim3 tb(32, 8);
  k_transpose<<<dim3(DOUT/32, DIN/32), tb, 0, stream>>>(Wq, Wq_t, DIN, DOUT);
  k_transpose<<<dim3(512/32,  DIN/32), tb, 0, stream>>>(Wk, Wkv_t, DIN, 512);
  k_transpose<<<dim3(512/32,  DIN/32), tb, 0, stream>>>(Wv, Wkv_t + (size_t)512*DIN, DIN, 512);
  k_transpose<<<dim3(DOUT/32, DOUT/32), tb, 0, stream>>>(Wo, Wo_t, DOUT, DOUT);

  k_gemm_bt<unsigned short><<<dim3(DOUT/128, M_/128), 256, 0, stream>>>(xb, Wq_t,  Qb,  M_, DOUT, DIN);
  k_gemm_bt<unsigned short><<<dim3(1024/128, M_/128), 256, 0, stream>>>(xb, Wkv_t, KVb, M_, 1024, DIN);

  k_rope<<<dim3(M_*H_*32/256), dim3(256), 0, stream>>>(Qb,  cosT, sinT, H_, DOUT);
  k_rope<<<dim3(M_*G_*32/256), dim3(256), 0, stream>>>(KVb, cosT, sinT, G_, 1024);

  k_attn<<<dim3(N_/64, H_, B_), dim3(256), 0, stream>>>(Qb, KVb, ctxb);

  k_gemm_bt<float><<<dim3(DOUT/128, M_/128), 256, 0, stream>>>(ctxb, Wo_t, out, M_, DOUT, DIN);
}

// Round 2
// 390.495 us; speedup vs baseline: 1.4475x; 1.4475x over previous
//
#include <hip/hip_runtime.h>
#include <hip/hip_bf16.h>
#include <stdint.h>

#define B_   2
#define N_   2048
#define DIN  2048
#define DOUT 2048
#define H_   32
#define G_   8
#define HD_  64
#define M_   (B_*N_)   // 4096

using short8 = __attribute__((ext_vector_type(8))) short;
using f32x4  = __attribute__((ext_vector_type(4))) float;
using f32x16 = __attribute__((ext_vector_type(16))) float;
using int4v  = __attribute__((ext_vector_type(4))) int;

__device__ __forceinline__ unsigned short f2bf(float f) {
  unsigned int u = __float_as_uint(f);
  unsigned int r = u + 0x7FFFu + ((u >> 16) & 1u);
  return (unsigned short)(r >> 16);
}
__device__ __forceinline__ float bf2f(unsigned short h) {
  return __uint_as_float(((unsigned int)h) << 16);
}

// ---------------- elementwise f32 -> bf16 (4 elems/thread) ----------------
__global__ void k_cvt(const float* __restrict__ in, unsigned short* __restrict__ out, int n4) {
  int i = blockIdx.x * 256 + threadIdx.x;
  if (i >= n4) return;
  float4 v = reinterpret_cast<const float4*>(in)[i];
  uint2 o;
  o.x = (unsigned int)f2bf(v.x) | ((unsigned int)f2bf(v.y) << 16);
  o.y = (unsigned int)f2bf(v.z) | ((unsigned int)f2bf(v.w) << 16);
  reinterpret_cast<uint2*>(out)[i] = o;
}

// ---------------- transpose + convert: W (R x C) f32 -> Wt (C x R) bf16 ----------------
__global__ void k_transpose(const float* __restrict__ W, unsigned short* __restrict__ Wt,
                            int R, int C) {
  __shared__ float tile[32][33];
  int c0 = blockIdx.x * 32, r0 = blockIdx.y * 32;
  int tx = threadIdx.x, ty = threadIdx.y;  // (32,8)
  #pragma unroll
  for (int j = 0; j < 4; ++j)
    tile[ty + j*8][tx] = W[(size_t)(r0 + ty + j*8) * C + c0 + tx];
  __syncthreads();
  #pragma unroll
  for (int j = 0; j < 4; ++j)
    Wt[(size_t)(c0 + ty + j*8) * R + r0 + tx] = f2bf(tile[tx][ty + j*8]);
}

// ---------------- bf16 V-transpose: KVb V-half -> Vt[(b*8+g)*64 + d][n] ----------------
__global__ void k_vtrans(const unsigned short* __restrict__ KV, unsigned short* __restrict__ Vt) {
  __shared__ unsigned short tile[32][33];
  int nt = blockIdx.x;   // 0..63 (n tile)
  int dt = blockIdx.y;   // 0..1  (d tile)
  int bg = blockIdx.z;   // 0..15 (b*8+g)
  int b = bg >> 3, g = bg & 7;
  int tx = threadIdx.x, ty = threadIdx.y;  // (32,8)
  const unsigned short* src = KV + (size_t)(b*2048 + nt*32) * 1024 + 512 + g*64 + dt*32;
  #pragma unroll
  for (int j = 0; j < 4; ++j)
    tile[ty + j*8][tx] = src[(size_t)(ty + j*8) * 1024 + tx];   // [n_local][d_local]
  __syncthreads();
  unsigned short* dst = Vt + ((size_t)bg*64 + dt*32) * (size_t)N_ + nt*32;
  #pragma unroll
  for (int j = 0; j < 4; ++j)
    dst[(size_t)(ty + j*8) * N_ + tx] = tile[tx][ty + j*8];     // [d_local][n_local]
}

// ---------------- in-place RoPE on bf16 (thread owns the (d, d+32) pair) ----------------
__global__ void k_rope(unsigned short* __restrict__ X, const float* __restrict__ cosT,
                       const float* __restrict__ sinT, int nheads, int rowStride) {
  int idx = blockIdx.x * 256 + threadIdx.x;
  int dp  = idx & 31;
  int hh  = (idx >> 5) % nheads;
  int row = idx / (32 * nheads);
  if (row >= M_) return;
  int n = row & (N_ - 1);
  float c = cosT[n*HD_ + dp], s = sinT[n*HD_ + dp];
  unsigned short* p = X + (size_t)row * rowStride + hh*HD_ + dp;
  float x1 = bf2f(p[0]), x2 = bf2f(p[32]);
  p[0]  = f2bf(x1*c - x2*s);
  p[32] = f2bf(x2*c + x1*s);
}

// ---------------- bf16 GEMM, B given transposed (Bt: N x K row-major) ----------------
template <typename OUT>
__global__ void __launch_bounds__(256)
k_gemm_bt(const unsigned short* __restrict__ A, const unsigned short* __restrict__ Bt,
          OUT* __restrict__ C, int M, int N, int K) {
  __shared__ unsigned short As[128 * 32];
  __shared__ unsigned short Bs[128 * 32];
  const int tid  = threadIdx.x;
  const int wid  = tid >> 6, l = tid & 63;
  const int lrow = l & 15,  lk = l >> 4;
  const int wm = wid >> 1,  wn = wid & 1;
  const int rowA0 = blockIdx.y * 128, rowB0 = blockIdx.x * 128;

  f32x4 acc[4][4];
  #pragma unroll
  for (int m = 0; m < 4; ++m)
    #pragma unroll
    for (int n = 0; n < 4; ++n)
      #pragma unroll
      for (int r = 0; r < 4; ++r) acc[m][n][r] = 0.f;

  int srow[2], scol[2];
  #pragma unroll
  for (int issue = 0; issue < 2; ++issue) {
    int slot = issue*4096 + wid*1024 + l*16;
    int row  = slot >> 6;
    int cp   = (slot >> 4) & 3;
    int sw   = (row & 3) ^ ((row >> 2) & 3);
    srow[issue] = row;
    scol[issue] = (cp ^ sw) * 8;
  }
  const int swr    = (lrow & 3) ^ ((lrow >> 2) & 3);
  const int rchunk = (lk ^ swr) * 8;

  for (int kt = 0; kt < K; kt += 32) {
    __syncthreads();
    #pragma unroll
    for (int issue = 0; issue < 2; ++issue) {
      const unsigned short* ga = A  + (size_t)(rowA0 + srow[issue]) * K + kt + scol[issue];
      const unsigned short* gb = Bt + (size_t)(rowB0 + srow[issue]) * K + kt + scol[issue];
      __builtin_amdgcn_global_load_lds(
          (const __attribute__((address_space(1))) unsigned int*)ga,
          (__attribute__((address_space(3))) unsigned int*)((char*)As + issue*4096 + wid*1024),
          16, 0, 0);
      __builtin_amdgcn_global_load_lds(
          (const __attribute__((address_space(1))) unsigned int*)gb,
          (__attribute__((address_space(3))) unsigned int*)((char*)Bs + issue*4096 + wid*1024),
          16, 0, 0);
    }
    asm volatile("s_waitcnt vmcnt(0)" ::: "memory");
    __syncthreads();

    short8 av[4], bv[4];
    #pragma unroll
    for (int m = 0; m < 4; ++m)
      av[m] = *reinterpret_cast<const short8*>(&As[(wm*64 + m*16 + lrow)*32 + rchunk]);
    #pragma unroll
    for (int n = 0; n < 4; ++n)
      bv[n] = *reinterpret_cast<const short8*>(&Bs[(wn*64 + n*16 + lrow)*32 + rchunk]);
    #pragma unroll
    for (int m = 0; m < 4; ++m)
      #pragma unroll
      for (int n = 0; n < 4; ++n)
        acc[m][n] = __builtin_amdgcn_mfma_f32_16x16x32_bf16(av[m], bv[n], acc[m][n], 0, 0, 0);
  }

  #pragma unroll
  for (int m = 0; m < 4; ++m) {
    int row0 = rowA0 + wm*64 + m*16 + lk*4;
    #pragma unroll
    for (int n = 0; n < 4; ++n) {
      int col = rowB0 + wn*64 + n*16 + lrow;
      #pragma unroll
      for (int r = 0; r < 4; ++r) {
        float v = acc[m][n][r];
        if constexpr (sizeof(OUT) == 2) C[(size_t)(row0 + r) * N + col] = (OUT)f2bf(v);
        else                            C[(size_t)(row0 + r) * N + col] = v;
      }
    }
  }
}

// ---------------- causal GQA flash attention, swapped-operand 32x32, 1 wave / 32 q-rows ----
// Zero LDS, zero barriers. Lane holds q = lane&31; S^T reg key map:
// ko(reg,hi) = (reg&3) + 8*(reg>>2) + 4*hi  (measured 32x32 C/D layout).
__global__ void __launch_bounds__(64)
k_attn(const unsigned short* __restrict__ Q, const unsigned short* __restrict__ KV,
       const unsigned short* __restrict__ Vt, unsigned short* __restrict__ ctx) {
  const int id = blockIdx.x;
  const int qt = id & 63;
  const int h  = (id >> 6) & 31;
  const int b  = id >> 11;
  const int g  = h >> 2;
  const int l  = threadIdx.x;
  const int lq = l & 31, hi = l >> 5;
  const int q0 = qt * 32;
  const float SC = 0.125f * 1.44269504088896f;  // softmax scale folded into log2 domain

  // Q fragments (B-operand): lane holds q-row q0+lq, hd chunks 16c + 8*hi .. +7
  const unsigned short* qp = Q + (size_t)(b*N_ + q0 + lq) * DOUT + h*HD_ + hi*8;
  short8 qf0 = *reinterpret_cast<const short8*>(qp);
  short8 qf1 = *reinterpret_cast<const short8*>(qp + 16);
  short8 qf2 = *reinterpret_cast<const short8*>(qp + 32);
  short8 qf3 = *reinterpret_cast<const short8*>(qp + 48);

  const unsigned short* kbase = KV + (size_t)(b*N_ + lq) * 1024 + g*HD_ + hi*8;
  const unsigned short* vbase = Vt + ((size_t)((b*8 + g)*64) + lq) * (size_t)N_ + hi*8;

  f32x16 acc0, acc1;
  #pragma unroll
  for (int r = 0; r < 16; ++r) { acc0[r] = 0.f; acc1[r] = 0.f; }
  float m_run = -3.0e38f, l_run = 0.f;

  for (int t = 0; t <= qt; ++t) {
    const int kv0 = t * 32;
    // K fragments (A-operand): row = key kv0+lq, same hd chunking as Q
    const unsigned short* kp = kbase + (size_t)kv0 * 1024;
    short8 kf0 = *reinterpret_cast<const short8*>(kp);
    short8 kf1 = *reinterpret_cast<const short8*>(kp + 16);
    short8 kf2 = *reinterpret_cast<const short8*>(kp + 32);
    short8 kf3 = *reinterpret_cast<const short8*>(kp + 48);
    // V^T fragments (A-operand of PV): row = d (32*dt + lq), keys 16*ks + 8*hi ..
    const unsigned short* vp = vbase + kv0;
    short8 v00 = *reinterpret_cast<const short8*>(vp);
    short8 v01 = *reinterpret_cast<const short8*>(vp + 16);
    short8 v10 = *reinterpret_cast<const short8*>(vp + (size_t)32*N_);
    short8 v11 = *reinterpret_cast<const short8*>(vp + (size_t)32*N_ + 16);

    f32x16 s;
    #pragma unroll
    for (int r = 0; r < 16; ++r) s[r] = 0.f;
    s = __builtin_amdgcn_mfma_f32_32x32x16_bf16(kf0, qf0, s, 0, 0, 0);
    s = __builtin_amdgcn_mfma_f32_32x32x16_bf16(kf1, qf1, s, 0, 0, 0);
    s = __builtin_amdgcn_mfma_f32_32x32x16_bf16(kf2, qf2, s, 0, 0, 0);
    s = __builtin_amdgcn_mfma_f32_32x32x16_bf16(kf3, qf3, s, 0, 0, 0);

    float u[16];
    #pragma unroll
    for (int r = 0; r < 16; ++r) u[r] = s[r] * SC;
    if (t == qt) {  // diagonal tile: mask keys ko > lq
      #pragma unroll
      for (int r = 0; r < 16; ++r) {
        const int ko = (r & 3) + 8*(r >> 2) + 4*hi;
        u[r] = (ko <= lq) ? u[r] : -3.0e38f;
      }
    }
    float mt = u[0];
    #pragma unroll
    for (int r = 1; r < 16; ++r) mt = fmaxf(mt, u[r]);
    mt = fmaxf(mt, __shfl_xor(mt, 32));
    const float nm = fmaxf(m_run, mt);
    const float fr = exp2f(m_run - nm);
    m_run = nm;

    // exp + row-sum + pack P to bf16 pairs (T12)
    unsigned int w[8];
    float ps = 0.f;
    #pragma unroll
    for (int i = 0; i < 8; ++i) {
      float p0 = exp2f(u[2*i]   - nm);
      float p1 = exp2f(u[2*i+1] - nm);
      ps += p0 + p1;
      asm("v_cvt_pk_bf16_f32 %0, %1, %2" : "=v"(w[i]) : "v"(p0), "v"(p1));
    }
    ps += __shfl_xor(ps, 32);
    l_run = l_run * fr + ps;

    unsigned int sw[8];
    #pragma unroll
    for (int i = 0; i < 8; ++i) sw[i] = (unsigned int)__shfl_xor((int)w[i], 32);

    // P fragments: slot (hi,j) of PV-mfma ks holds P[q][16*ks + 8*hi + j]
    int4v pa0i, pa1i;
    pa0i[0] = (int)(hi ? sw[2] : w[0]);
    pa0i[1] = (int)(hi ? sw[3] : w[1]);
    pa0i[2] = (int)(hi ? w[2] : sw[0]);
    pa0i[3] = (int)(hi ? w[3] : sw[1]);
    pa1i[0] = (int)(hi ? sw[6] : w[4]);
    pa1i[1] = (int)(hi ? sw[7] : w[5]);
    pa1i[2] = (int)(hi ? w[6] : sw[4]);
    pa1i[3] = (int)(hi ? w[7] : sw[5]);
    short8 pa0 = __builtin_bit_cast(short8, pa0i);
    short8 pa1 = __builtin_bit_cast(short8, pa1i);

    #pragma unroll
    for (int r = 0; r < 16; ++r) { acc0[r] *= fr; acc1[r] *= fr; }

    // O^T = V^T * P^T : D col = q (lane&31), D row = d-offset (matches A rows)
    acc0 = __builtin_amdgcn_mfma_f32_32x32x16_bf16(v00, pa0, acc0, 0, 0, 0);
    acc0 = __builtin_amdgcn_mfma_f32_32x32x16_bf16(v01, pa1, acc0, 0, 0, 0);
    acc1 = __builtin_amdgcn_mfma_f32_32x32x16_bf16(v10, pa0, acc1, 0, 0, 0);
    acc1 = __builtin_amdgcn_mfma_f32_32x32x16_bf16(v11, pa1, acc1, 0, 0, 0);
  }

  const float rl = 1.f / l_run;
  unsigned short* op = ctx + (size_t)(b*N_ + q0 + lq) * DOUT + h*HD_ + 4*hi;
  #pragma unroll
  for (int dt = 0; dt < 2; ++dt) {
    #pragma unroll
    for (int rq = 0; rq < 4; ++rq) {
      const float a0 = (dt ? acc1[4*rq+0] : acc0[4*rq+0]) * rl;
      const float a1 = (dt ? acc1[4*rq+1] : acc0[4*rq+1]) * rl;
      const float a2 = (dt ? acc1[4*rq+2] : acc0[4*rq+2]) * rl;
      const float a3 = (dt ? acc1[4*rq+3] : acc0[4*rq+3]) * rl;
      ushort4 st;
      st.x = f2bf(a0); st.y = f2bf(a1); st.z = f2bf(a2); st.w = f2bf(a3);
      *reinterpret_cast<ushort4*>(op + dt*32 + rq*8) = st;
    }
  }
}

// ---------------- launcher ----------------
extern "C" void kernel_launch(void* const* d_in, const int* in_sizes, int n_in,
                              void* d_out, int out_size, void* d_ws, size_t ws_size,
                              hipStream_t stream) {
  const float* x    = (const float*)d_in[0];
  const float* cosT = (const float*)d_in[1];
  const float* sinT = (const float*)d_in[2];
  const float* Wq   = (const float*)d_in[4];
  const float* Wk   = (const float*)d_in[5];
  const float* Wv   = (const float*)d_in[6];
  const float* Wo   = (const float*)d_in[7];
  float* out = (float*)d_out;

  char* ws = (char*)d_ws;
  unsigned short* xb    = (unsigned short*)(ws);               // 16,777,216 B (reused as ctxb)
  unsigned short* ctxb  = xb;
  unsigned short* Wq_t  = (unsigned short*)(ws + 16777216);    //  8,388,608 B (reused as Vt)
  unsigned short* Vt    = Wq_t;                                 //  4,194,304 B needed
  unsigned short* Wkv_t = (unsigned short*)(ws + 25165824);    //  4,194,304 B
  unsigned short* Wo_t  = (unsigned short*)(ws + 29360128);    //  8,388,608 B
  unsigned short* Qb    = (unsigned short*)(ws + 37748736);    // 16,777,216 B
  unsigned short* KVb   = (unsigned short*)(ws + 54525952);    //  8,388,608 B

  k_cvt<<<dim3(M_*DIN/4/256), dim3(256), 0, stream>>>(x, xb, M_*DIN/4);

  dim3 tb(32, 8);
  k_transpose<<<dim3(DOUT/32, DIN/32), tb, 0, stream>>>(Wq, Wq_t, DIN, DOUT);
  k_transpose<<<dim3(512/32,  DIN/32), tb, 0, stream>>>(Wk, Wkv_t, DIN, 512);
  k_transpose<<<dim3(512/32,  DIN/32), tb, 0, stream>>>(Wv, Wkv_t + (size_t)512*DIN, DIN, 512);
  k_transpose<<<dim3(DOUT/32, DOUT/32), tb, 0, stream>>>(Wo, Wo_t, DOUT, DOUT);

  k_gemm_bt<unsigned short><<<dim3(DOUT/128, M_/128), 256, 0, stream>>>(xb, Wq_t,  Qb,  M_, DOUT, DIN);
  k_gemm_bt<unsigned short><<<dim3(1024/128, M_/128), 256, 0, stream>>>(xb, Wkv_t, KVb, M_, 1024, DIN);

  k_rope<<<dim3(M_*H_*32/256), dim3(256), 0, stream>>>(Qb,  cosT, sinT, H_, DOUT);
  k_rope<<<dim3(M_*G_*32/256), dim3(256), 0, stream>>>(KVb, cosT, sinT, G_, 1024);

  // V^T into the (now dead) Wq_t region
  k_vtrans<<<dim3(64, 2, 16), tb, 0, stream>>>(KVb, Vt);

  k_attn<<<dim3(4096), dim3(64), 0, stream>>>(Qb, KVb, Vt, ctxb);

  k_gemm_bt<float><<<dim3(DOUT/128, M_/128), 256, 0, stream>>>(ctxb, Wo_t, out, M_, DOUT, DIN);
}

// Round 3
// 357.356 us; speedup vs baseline: 1.5818x; 1.0927x over previous
//
#include <hip/hip_runtime.h>
#include <hip/hip_bf16.h>
#include <stdint.h>

#define B_   2
#define N_   2048
#define DIN  2048
#define DOUT 2048
#define H_   32
#define G_   8
#define HD_  64
#define M_   (B_*N_)   // 4096

using short8 = __attribute__((ext_vector_type(8))) short;
using f32x4  = __attribute__((ext_vector_type(4))) float;
using f32x16 = __attribute__((ext_vector_type(16))) float;
using int4v  = __attribute__((ext_vector_type(4))) int;

__device__ __forceinline__ unsigned short f2bf(float f) {
  unsigned int u = __float_as_uint(f);
  unsigned int r = u + 0x7FFFu + ((u >> 16) & 1u);
  return (unsigned short)(r >> 16);
}
__device__ __forceinline__ float bf2f(unsigned short h) {
  return __uint_as_float(((unsigned int)h) << 16);
}

// ---------------- elementwise f32 -> bf16 (4 elems/thread) ----------------
__global__ void k_cvt(const float* __restrict__ in, unsigned short* __restrict__ out, int n4) {
  int i = blockIdx.x * 256 + threadIdx.x;
  if (i >= n4) return;
  float4 v = reinterpret_cast<const float4*>(in)[i];
  uint2 o;
  o.x = (unsigned int)f2bf(v.x) | ((unsigned int)f2bf(v.y) << 16);
  o.y = (unsigned int)f2bf(v.z) | ((unsigned int)f2bf(v.w) << 16);
  reinterpret_cast<uint2*>(out)[i] = o;
}

// ---------------- transpose + convert: W (R x C) f32 -> Wt (C x R) bf16 ----------------
__global__ void k_transpose(const float* __restrict__ W, unsigned short* __restrict__ Wt,
                            int R, int C) {
  __shared__ float tile[32][33];
  int c0 = blockIdx.x * 32, r0 = blockIdx.y * 32;
  int tx = threadIdx.x, ty = threadIdx.y;  // (32,8)
  #pragma unroll
  for (int j = 0; j < 4; ++j)
    tile[ty + j*8][tx] = W[(size_t)(r0 + ty + j*8) * C + c0 + tx];
  __syncthreads();
  #pragma unroll
  for (int j = 0; j < 4; ++j)
    Wt[(size_t)(c0 + ty + j*8) * R + r0 + tx] = f2bf(tile[tx][ty + j*8]);
}

// ---------------- bf16 V-transpose: KVb V-half -> Vt[(b*8+g)*64 + d][n] ----------------
__global__ void k_vtrans(const unsigned short* __restrict__ KV, unsigned short* __restrict__ Vt) {
  __shared__ unsigned short tile[32][33];
  int nt = blockIdx.x;   // 0..63 (n tile)
  int dt = blockIdx.y;   // 0..1  (d tile)
  int bg = blockIdx.z;   // 0..15 (b*8+g)
  int b = bg >> 3, g = bg & 7;
  int tx = threadIdx.x, ty = threadIdx.y;  // (32,8)
  const unsigned short* src = KV + (size_t)(b*2048 + nt*32) * 1024 + 512 + g*64 + dt*32;
  #pragma unroll
  for (int j = 0; j < 4; ++j)
    tile[ty + j*8][tx] = src[(size_t)(ty + j*8) * 1024 + tx];   // [n_local][d_local]
  __syncthreads();
  unsigned short* dst = Vt + ((size_t)bg*64 + dt*32) * (size_t)N_ + nt*32;
  #pragma unroll
  for (int j = 0; j < 4; ++j)
    dst[(size_t)(ty + j*8) * N_ + tx] = tile[tx][ty + j*8];     // [d_local][n_local]
}

// ---------------- in-place RoPE on bf16, optional output scale ----------------
__global__ void k_rope(unsigned short* __restrict__ X, const float* __restrict__ cosT,
                       const float* __restrict__ sinT, int nheads, int rowStride, float scale) {
  int idx = blockIdx.x * 256 + threadIdx.x;
  int dp  = idx & 31;
  int hh  = (idx >> 5) % nheads;
  int row = idx / (32 * nheads);
  if (row >= M_) return;
  int n = row & (N_ - 1);
  float c = cosT[n*HD_ + dp] * scale, s = sinT[n*HD_ + dp] * scale;
  unsigned short* p = X + (size_t)row * rowStride + hh*HD_ + dp;
  float x1 = bf2f(p[0]), x2 = bf2f(p[32]);
  p[0]  = f2bf(x1*c - x2*s);
  p[32] = f2bf(x2*c + x1*s);
}

// ---------------- bf16 GEMM, B given transposed (Bt: N x K row-major) ----------------
template <typename OUT>
__global__ void __launch_bounds__(256)
k_gemm_bt(const unsigned short* __restrict__ A, const unsigned short* __restrict__ Bt,
          OUT* __restrict__ C, int M, int N, int K) {
  __shared__ unsigned short As[128 * 32];
  __shared__ unsigned short Bs[128 * 32];
  const int tid  = threadIdx.x;
  const int wid  = tid >> 6, l = tid & 63;
  const int lrow = l & 15,  lk = l >> 4;
  const int wm = wid >> 1,  wn = wid & 1;
  const int rowA0 = blockIdx.y * 128, rowB0 = blockIdx.x * 128;

  f32x4 acc[4][4];
  #pragma unroll
  for (int m = 0; m < 4; ++m)
    #pragma unroll
    for (int n = 0; n < 4; ++n)
      #pragma unroll
      for (int r = 0; r < 4; ++r) acc[m][n][r] = 0.f;

  int srow[2], scol[2];
  #pragma unroll
  for (int issue = 0; issue < 2; ++issue) {
    int slot = issue*4096 + wid*1024 + l*16;
    int row  = slot >> 6;
    int cp   = (slot >> 4) & 3;
    int sw   = (row & 3) ^ ((row >> 2) & 3);
    srow[issue] = row;
    scol[issue] = (cp ^ sw) * 8;
  }
  const int swr    = (lrow & 3) ^ ((lrow >> 2) & 3);
  const int rchunk = (lk ^ swr) * 8;

  for (int kt = 0; kt < K; kt += 32) {
    __syncthreads();
    #pragma unroll
    for (int issue = 0; issue < 2; ++issue) {
      const unsigned short* ga = A  + (size_t)(rowA0 + srow[issue]) * K + kt + scol[issue];
      const unsigned short* gb = Bt + (size_t)(rowB0 + srow[issue]) * K + kt + scol[issue];
      __builtin_amdgcn_global_load_lds(
          (const __attribute__((address_space(1))) unsigned int*)ga,
          (__attribute__((address_space(3))) unsigned int*)((char*)As + issue*4096 + wid*1024),
          16, 0, 0);
      __builtin_amdgcn_global_load_lds(
          (const __attribute__((address_space(1))) unsigned int*)gb,
          (__attribute__((address_space(3))) unsigned int*)((char*)Bs + issue*4096 + wid*1024),
          16, 0, 0);
    }
    asm volatile("s_waitcnt vmcnt(0)" ::: "memory");
    __syncthreads();

    short8 av[4], bv[4];
    #pragma unroll
    for (int m = 0; m < 4; ++m)
      av[m] = *reinterpret_cast<const short8*>(&As[(wm*64 + m*16 + lrow)*32 + rchunk]);
    #pragma unroll
    for (int n = 0; n < 4; ++n)
      bv[n] = *reinterpret_cast<const short8*>(&Bs[(wn*64 + n*16 + lrow)*32 + rchunk]);
    #pragma unroll
    for (int m = 0; m < 4; ++m)
      #pragma unroll
      for (int n = 0; n < 4; ++n)
        acc[m][n] = __builtin_amdgcn_mfma_f32_16x16x32_bf16(av[m], bv[n], acc[m][n], 0, 0, 0);
  }

  #pragma unroll
  for (int m = 0; m < 4; ++m) {
    int row0 = rowA0 + wm*64 + m*16 + lk*4;
    #pragma unroll
    for (int n = 0; n < 4; ++n) {
      int col = rowB0 + wn*64 + n*16 + lrow;
      #pragma unroll
      for (int r = 0; r < 4; ++r) {
        float v = acc[m][n][r];
        if constexpr (sizeof(OUT) == 2) C[(size_t)(row0 + r) * N + col] = (OUT)f2bf(v);
        else                            C[(size_t)(row0 + r) * N + col] = v;
      }
    }
  }
}

// ---------------- causal GQA flash attention v3 ----------------
// 1 wave per PAIR of q-tiles {pr, 63-pr} (65 K-tiles/wave, scheduler-independent balance).
// Shared K/V stream feeds both q-tiles (stream A range ⊂ stream B range).
// Ping-pong K/V prefetch; Q pre-scaled by 0.125*log2e; defer-max (T13); permlane P-pack (T12).
__global__ void __launch_bounds__(64, 2)
k_attn(const unsigned short* __restrict__ Q, const unsigned short* __restrict__ KV,
       const unsigned short* __restrict__ Vt, unsigned short* __restrict__ ctx) {
  const int id = blockIdx.x;          // 0..2047
  const int b  = id >> 10;
  const int h  = (id >> 5) & 31;
  const int pr = id & 31;
  const int g  = h >> 2;
  const int l  = threadIdx.x;
  const int lq = l & 31, hi = l >> 5;
  const int qtA = pr, qtB = 63 - pr;

  // Q fragments (B-operand), already scaled by 0.125*log2e at RoPE time
  const unsigned short* qpA = Q + (size_t)(b*N_ + qtA*32 + lq) * DOUT + h*HD_ + hi*8;
  const unsigned short* qpB = Q + (size_t)(b*N_ + qtB*32 + lq) * DOUT + h*HD_ + hi*8;
  short8 qA0 = *reinterpret_cast<const short8*>(qpA);
  short8 qA1 = *reinterpret_cast<const short8*>(qpA + 16);
  short8 qA2 = *reinterpret_cast<const short8*>(qpA + 32);
  short8 qA3 = *reinterpret_cast<const short8*>(qpA + 48);
  short8 qB0 = *reinterpret_cast<const short8*>(qpB);
  short8 qB1 = *reinterpret_cast<const short8*>(qpB + 16);
  short8 qB2 = *reinterpret_cast<const short8*>(qpB + 32);
  short8 qB3 = *reinterpret_cast<const short8*>(qpB + 48);

  const unsigned short* kbase = KV + (size_t)(b*N_ + lq) * 1024 + g*HD_ + hi*8;
  const unsigned short* vbase = Vt + ((size_t)((b*8 + g)*64) + lq) * (size_t)N_ + hi*8;

  f32x16 aA0, aA1, aB0, aB1;
  #pragma unroll
  for (int r = 0; r < 16; ++r) { aA0[r] = 0.f; aA1[r] = 0.f; aB0[r] = 0.f; aB1[r] = 0.f; }
  float mA = -3.0e38f, lA = 0.f, mB = -3.0e38f, lB = 0.f;

  short8 k0a, k0b, k0c, k0d, v0a, v0b, v0c, v0d;   // ping
  short8 k1a, k1b, k1c, k1d, v1a, v1b, v1c, v1d;   // pong

  auto loadKV = [&](int t, short8& ka, short8& kb, short8& kc, short8& kd,
                            short8& va, short8& vb, short8& vc, short8& vd) {
    const unsigned short* kp = kbase + (size_t)(t*32) * 1024;
    ka = *reinterpret_cast<const short8*>(kp);
    kb = *reinterpret_cast<const short8*>(kp + 16);
    kc = *reinterpret_cast<const short8*>(kp + 32);
    kd = *reinterpret_cast<const short8*>(kp + 48);
    const unsigned short* vp = vbase + t*32;
    va = *reinterpret_cast<const short8*>(vp);
    vb = *reinterpret_cast<const short8*>(vp + 16);
    vc = *reinterpret_cast<const short8*>(vp + (size_t)32*N_);
    vd = *reinterpret_cast<const short8*>(vp + (size_t)32*N_ + 16);
  };

  auto soft_pv = [&](const f32x16& s, bool diag,
                     short8& va, short8& vb, short8& vc, short8& vd,
                     f32x16& acc0, f32x16& acc1, float& m, float& lsum) {
    float u[16];
    if (diag) {
      #pragma unroll
      for (int r = 0; r < 16; ++r) {
        const int ko = (r & 3) + 8*(r >> 2) + 4*hi;
        u[r] = (ko <= lq) ? s[r] : -3.0e38f;
      }
    } else {
      #pragma unroll
      for (int r = 0; r < 16; ++r) u[r] = s[r];
    }
    // max tree (max3-friendly)
    float t0 = fmaxf(fmaxf(u[0], u[1]), u[2]);
    float t1 = fmaxf(fmaxf(u[3], u[4]), u[5]);
    float t2 = fmaxf(fmaxf(u[6], u[7]), u[8]);
    float t3 = fmaxf(fmaxf(u[9], u[10]), u[11]);
    float t4 = fmaxf(fmaxf(u[12], u[13]), u[14]);
    float mt = fmaxf(fmaxf(fmaxf(t0, t1), fmaxf(t2, t3)), fmaxf(t4, u[15]));
    mt = fmaxf(mt, __shfl_xor(mt, 32));
    if (!__all(mt <= m + 8.f)) {          // T13 defer-max
      float nm = fmaxf(m, mt);
      float fr = exp2f(m - nm);
      m = nm;
      lsum *= fr;
      #pragma unroll
      for (int r = 0; r < 16; ++r) { acc0[r] *= fr; acc1[r] *= fr; }
    }
    unsigned int w[8];
    float ps = 0.f;
    #pragma unroll
    for (int i = 0; i < 8; ++i) {
      float p0 = exp2f(u[2*i]   - m);
      float p1 = exp2f(u[2*i+1] - m);
      ps += p0 + p1;
      asm("v_cvt_pk_bf16_f32 %0, %1, %2" : "=v"(w[i]) : "v"(p0), "v"(p1));
    }
    ps += __shfl_xor(ps, 32);
    lsum += ps;

    // T12: permlane32_swap builds both P fragment words per swap
    unsigned int x0 = w[0], x1 = w[1], y0 = w[2], y1 = w[3];
    asm("v_permlane32_swap_b32 %0, %1" : "+v"(x0), "+v"(y0));
    asm("v_permlane32_swap_b32 %0, %1" : "+v"(x1), "+v"(y1));
    unsigned int x2 = w[4], x3 = w[5], y2 = w[6], y3 = w[7];
    asm("v_permlane32_swap_b32 %0, %1" : "+v"(x2), "+v"(y2));
    asm("v_permlane32_swap_b32 %0, %1" : "+v"(x3), "+v"(y3));
    int4v p0i, p1i;
    p0i[0] = (int)x0; p0i[1] = (int)x1; p0i[2] = (int)y0; p0i[3] = (int)y1;
    p1i[0] = (int)x2; p1i[1] = (int)x3; p1i[2] = (int)y2; p1i[3] = (int)y3;
    short8 pa0 = __builtin_bit_cast(short8, p0i);
    short8 pa1 = __builtin_bit_cast(short8, p1i);

    acc0 = __builtin_amdgcn_mfma_f32_32x32x16_bf16(va, pa0, acc0, 0, 0, 0);
    acc0 = __builtin_amdgcn_mfma_f32_32x32x16_bf16(vb, pa1, acc0, 0, 0, 0);
    acc1 = __builtin_amdgcn_mfma_f32_32x32x16_bf16(vc, pa0, acc1, 0, 0, 0);
    acc1 = __builtin_amdgcn_mfma_f32_32x32x16_bf16(vd, pa1, acc1, 0, 0, 0);
  };

  auto body = [&](int t, short8& ka, short8& kb, short8& kc, short8& kd,
                         short8& va, short8& vb, short8& vc, short8& vd) {
    f32x16 sB;
    #pragma unroll
    for (int r = 0; r < 16; ++r) sB[r] = 0.f;
    sB = __builtin_amdgcn_mfma_f32_32x32x16_bf16(ka, qB0, sB, 0, 0, 0);
    sB = __builtin_amdgcn_mfma_f32_32x32x16_bf16(kb, qB1, sB, 0, 0, 0);
    sB = __builtin_amdgcn_mfma_f32_32x32x16_bf16(kc, qB2, sB, 0, 0, 0);
    sB = __builtin_amdgcn_mfma_f32_32x32x16_bf16(kd, qB3, sB, 0, 0, 0);
    if (t <= qtA) {
      f32x16 sA;
      #pragma unroll
      for (int r = 0; r < 16; ++r) sA[r] = 0.f;
      sA = __builtin_amdgcn_mfma_f32_32x32x16_bf16(ka, qA0, sA, 0, 0, 0);
      sA = __builtin_amdgcn_mfma_f32_32x32x16_bf16(kb, qA1, sA, 0, 0, 0);
      sA = __builtin_amdgcn_mfma_f32_32x32x16_bf16(kc, qA2, sA, 0, 0, 0);
      sA = __builtin_amdgcn_mfma_f32_32x32x16_bf16(kd, qA3, sA, 0, 0, 0);
      soft_pv(sB, false, va, vb, vc, vd, aB0, aB1, mB, lB);
      soft_pv(sA, t == qtA, va, vb, vc, vd, aA0, aA1, mA, lA);
    } else {
      soft_pv(sB, t == qtB, va, vb, vc, vd, aB0, aB1, mB, lB);
    }
  };

  loadKV(0, k0a, k0b, k0c, k0d, v0a, v0b, v0c, v0d);
  int t = 0;
  while (true) {
    if (t + 1 <= qtB) loadKV(t + 1, k1a, k1b, k1c, k1d, v1a, v1b, v1c, v1d);
    body(t, k0a, k0b, k0c, k0d, v0a, v0b, v0c, v0d);
    if (++t > qtB) break;
    if (t + 1 <= qtB) loadKV(t + 1, k0a, k0b, k0c, k0d, v0a, v0b, v0c, v0d);
    body(t, k1a, k1b, k1c, k1d, v1a, v1b, v1c, v1d);
    if (++t > qtB) break;
  }

  // epilogue: write both streams
  {
    const float rl = 1.f / lA;
    unsigned short* op = ctx + (size_t)(b*N_ + qtA*32 + lq) * DOUT + h*HD_ + 4*hi;
    #pragma unroll
    for (int dt = 0; dt < 2; ++dt)
      #pragma unroll
      for (int rq = 0; rq < 4; ++rq) {
        const float a0 = (dt ? aA1[4*rq+0] : aA0[4*rq+0]) * rl;
        const float a1 = (dt ? aA1[4*rq+1] : aA0[4*rq+1]) * rl;
        const float a2 = (dt ? aA1[4*rq+2] : aA0[4*rq+2]) * rl;
        const float a3 = (dt ? aA1[4*rq+3] : aA0[4*rq+3]) * rl;
        ushort4 st;
        st.x = f2bf(a0); st.y = f2bf(a1); st.z = f2bf(a2); st.w = f2bf(a3);
        *reinterpret_cast<ushort4*>(op + dt*32 + rq*8) = st;
      }
  }
  {
    const float rl = 1.f / lB;
    unsigned short* op = ctx + (size_t)(b*N_ + qtB*32 + lq) * DOUT + h*HD_ + 4*hi;
    #pragma unroll
    for (int dt = 0; dt < 2; ++dt)
      #pragma unroll
      for (int rq = 0; rq < 4; ++rq) {
        const float a0 = (dt ? aB1[4*rq+0] : aB0[4*rq+0]) * rl;
        const float a1 = (dt ? aB1[4*rq+1] : aB0[4*rq+1]) * rl;
        const float a2 = (dt ? aB1[4*rq+2] : aB0[4*rq+2]) * rl;
        const float a3 = (dt ? aB1[4*rq+3] : aB0[4*rq+3]) * rl;
        ushort4 st;
        st.x = f2bf(a0); st.y = f2bf(a1); st.z = f2bf(a2); st.w = f2bf(a3);
        *reinterpret_cast<ushort4*>(op + dt*32 + rq*8) = st;
      }
  }
}

// ---------------- launcher ----------------
extern "C" void kernel_launch(void* const* d_in, const int* in_sizes, int n_in,
                              void* d_out, int out_size, void* d_ws, size_t ws_size,
                              hipStream_t stream) {
  const float* x    = (const float*)d_in[0];
  const float* cosT = (const float*)d_in[1];
  const float* sinT = (const float*)d_in[2];
  const float* Wq   = (const float*)d_in[4];
  const float* Wk   = (const float*)d_in[5];
  const float* Wv   = (const float*)d_in[6];
  const float* Wo   = (const float*)d_in[7];
  float* out = (float*)d_out;

  char* ws = (char*)d_ws;
  unsigned short* xb    = (unsigned short*)(ws);               // 16 MB (reused as ctxb)
  unsigned short* ctxb  = xb;
  unsigned short* Wq_t  = (unsigned short*)(ws + 16777216);    // 8 MB (reused as Vt)
  unsigned short* Vt    = Wq_t;
  unsigned short* Wkv_t = (unsigned short*)(ws + 25165824);    // 4 MB
  unsigned short* Wo_t  = (unsigned short*)(ws + 29360128);    // 8 MB
  unsigned short* Qb    = (unsigned short*)(ws + 37748736);    // 16 MB
  unsigned short* KVb   = (unsigned short*)(ws + 54525952);    // 8 MB

  k_cvt<<<dim3(M_*DIN/4/256), dim3(256), 0, stream>>>(x, xb, M_*DIN/4);

  dim3 tb(32, 8);
  k_transpose<<<dim3(DOUT/32, DIN/32), tb, 0, stream>>>(Wq, Wq_t, DIN, DOUT);
  k_transpose<<<dim3(512/32,  DIN/32), tb, 0, stream>>>(Wk, Wkv_t, DIN, 512);
  k_transpose<<<dim3(512/32,  DIN/32), tb, 0, stream>>>(Wv, Wkv_t + (size_t)512*DIN, DIN, 512);
  k_transpose<<<dim3(DOUT/32, DOUT/32), tb, 0, stream>>>(Wo, Wo_t, DOUT, DOUT);

  k_gemm_bt<unsigned short><<<dim3(DOUT/128, M_/128), 256, 0, stream>>>(xb, Wq_t,  Qb,  M_, DOUT, DIN);
  k_gemm_bt<unsigned short><<<dim3(1024/128, M_/128), 256, 0, stream>>>(xb, Wkv_t, KVb, M_, 1024, DIN);

  const float QSCALE = 0.125f * 1.44269504088896f;   // 1/sqrt(64) * log2(e)
  k_rope<<<dim3(M_*H_*32/256), dim3(256), 0, stream>>>(Qb,  cosT, sinT, H_, DOUT, QSCALE);
  k_rope<<<dim3(M_*G_*32/256), dim3(256), 0, stream>>>(KVb, cosT, sinT, G_, 1024, 1.0f);

  k_vtrans<<<dim3(64, 2, 16), tb, 0, stream>>>(KVb, Vt);

  k_attn<<<dim3(2048), dim3(64), 0, stream>>>(Qb, KVb, Vt, ctxb);

  k_gemm_bt<float><<<dim3(DOUT/128, M_/128), 256, 0, stream>>>(ctxb, Wo_t, out, M_, DOUT, DIN);
}

// Round 4
// 332.271 us; speedup vs baseline: 1.7012x; 1.0755x over previous
//
#include <hip/hip_runtime.h>
#include <hip/hip_bf16.h>
#include <stdint.h>

#define B_   2
#define N_   2048
#define DIN  2048
#define DOUT 2048
#define H_   32
#define G_   8
#define HD_  64
#define M_   (B_*N_)   // 4096

using short8 = __attribute__((ext_vector_type(8))) short;
using f32x4  = __attribute__((ext_vector_type(4))) float;
using f32x16 = __attribute__((ext_vector_type(16))) float;
using int4v  = __attribute__((ext_vector_type(4))) int;

__device__ __forceinline__ unsigned short f2bf(float f) {
  unsigned int u = __float_as_uint(f);
  unsigned int r = u + 0x7FFFu + ((u >> 16) & 1u);
  return (unsigned short)(r >> 16);
}
__device__ __forceinline__ float bf2f(unsigned short h) {
  return __uint_as_float(((unsigned int)h) << 16);
}

// ---------------- elementwise f32 -> bf16 (4 elems/thread) ----------------
__global__ void k_cvt(const float* __restrict__ in, unsigned short* __restrict__ out, int n4) {
  int i = blockIdx.x * 256 + threadIdx.x;
  if (i >= n4) return;
  float4 v = reinterpret_cast<const float4*>(in)[i];
  uint2 o;
  o.x = (unsigned int)f2bf(v.x) | ((unsigned int)f2bf(v.y) << 16);
  o.y = (unsigned int)f2bf(v.z) | ((unsigned int)f2bf(v.w) << 16);
  reinterpret_cast<uint2*>(out)[i] = o;
}

// ---------------- transpose + convert: W (R x C) f32 -> Wt (C x R) bf16 ----------------
__global__ void k_transpose(const float* __restrict__ W, unsigned short* __restrict__ Wt,
                            int R, int C) {
  __shared__ float tile[32][33];
  int c0 = blockIdx.x * 32, r0 = blockIdx.y * 32;
  int tx = threadIdx.x, ty = threadIdx.y;  // (32,8)
  #pragma unroll
  for (int j = 0; j < 4; ++j)
    tile[ty + j*8][tx] = W[(size_t)(r0 + ty + j*8) * C + c0 + tx];
  __syncthreads();
  #pragma unroll
  for (int j = 0; j < 4; ++j)
    Wt[(size_t)(c0 + ty + j*8) * R + r0 + tx] = f2bf(tile[tx][ty + j*8]);
}

// ---------------- bf16 V-transpose: KVb V-half -> Vt[(b*8+g)*64 + d][n] ----------------
__global__ void k_vtrans(const unsigned short* __restrict__ KV, unsigned short* __restrict__ Vt) {
  __shared__ unsigned short tile[32][33];
  int nt = blockIdx.x;   // 0..63 (n tile)
  int dt = blockIdx.y;   // 0..1  (d tile)
  int bg = blockIdx.z;   // 0..15 (b*8+g)
  int b = bg >> 3, g = bg & 7;
  int tx = threadIdx.x, ty = threadIdx.y;  // (32,8)
  const unsigned short* src = KV + (size_t)(b*2048 + nt*32) * 1024 + 512 + g*64 + dt*32;
  #pragma unroll
  for (int j = 0; j < 4; ++j)
    tile[ty + j*8][tx] = src[(size_t)(ty + j*8) * 1024 + tx];   // [n_local][d_local]
  __syncthreads();
  unsigned short* dst = Vt + ((size_t)bg*64 + dt*32) * (size_t)N_ + nt*32;
  #pragma unroll
  for (int j = 0; j < 4; ++j)
    dst[(size_t)(ty + j*8) * N_ + tx] = tile[tx][ty + j*8];     // [d_local][n_local]
}

// ---------------- in-place RoPE on bf16, optional output scale ----------------
__global__ void k_rope(unsigned short* __restrict__ X, const float* __restrict__ cosT,
                       const float* __restrict__ sinT, int nheads, int rowStride, float scale) {
  int idx = blockIdx.x * 256 + threadIdx.x;
  int dp  = idx & 31;
  int hh  = (idx >> 5) % nheads;
  int row = idx / (32 * nheads);
  if (row >= M_) return;
  int n = row & (N_ - 1);
  float c = cosT[n*HD_ + dp] * scale, s = sinT[n*HD_ + dp] * scale;
  unsigned short* p = X + (size_t)row * rowStride + hh*HD_ + dp;
  float x1 = bf2f(p[0]), x2 = bf2f(p[32]);
  p[0]  = f2bf(x1*c - x2*s);
  p[32] = f2bf(x2*c + x1*s);
}

// ---------------- bf16 GEMM, B given transposed (Bt: N x K row-major) ----------------
template <typename OUT>
__global__ void __launch_bounds__(256)
k_gemm_bt(const unsigned short* __restrict__ A, const unsigned short* __restrict__ Bt,
          OUT* __restrict__ C, int M, int N, int K) {
  __shared__ unsigned short As[128 * 32];
  __shared__ unsigned short Bs[128 * 32];
  const int tid  = threadIdx.x;
  const int wid  = tid >> 6, l = tid & 63;
  const int lrow = l & 15,  lk = l >> 4;
  const int wm = wid >> 1,  wn = wid & 1;
  const int rowA0 = blockIdx.y * 128, rowB0 = blockIdx.x * 128;

  f32x4 acc[4][4];
  #pragma unroll
  for (int m = 0; m < 4; ++m)
    #pragma unroll
    for (int n = 0; n < 4; ++n)
      #pragma unroll
      for (int r = 0; r < 4; ++r) acc[m][n][r] = 0.f;

  int srow[2], scol[2];
  #pragma unroll
  for (int issue = 0; issue < 2; ++issue) {
    int slot = issue*4096 + wid*1024 + l*16;
    int row  = slot >> 6;
    int cp   = (slot >> 4) & 3;
    int sw   = (row & 3) ^ ((row >> 2) & 3);
    srow[issue] = row;
    scol[issue] = (cp ^ sw) * 8;
  }
  const int swr    = (lrow & 3) ^ ((lrow >> 2) & 3);
  const int rchunk = (lk ^ swr) * 8;

  for (int kt = 0; kt < K; kt += 32) {
    __syncthreads();
    #pragma unroll
    for (int issue = 0; issue < 2; ++issue) {
      const unsigned short* ga = A  + (size_t)(rowA0 + srow[issue]) * K + kt + scol[issue];
      const unsigned short* gb = Bt + (size_t)(rowB0 + srow[issue]) * K + kt + scol[issue];
      __builtin_amdgcn_global_load_lds(
          (const __attribute__((address_space(1))) unsigned int*)ga,
          (__attribute__((address_space(3))) unsigned int*)((char*)As + issue*4096 + wid*1024),
          16, 0, 0);
      __builtin_amdgcn_global_load_lds(
          (const __attribute__((address_space(1))) unsigned int*)gb,
          (__attribute__((address_space(3))) unsigned int*)((char*)Bs + issue*4096 + wid*1024),
          16, 0, 0);
    }
    asm volatile("s_waitcnt vmcnt(0)" ::: "memory");
    __syncthreads();

    short8 av[4], bv[4];
    #pragma unroll
    for (int m = 0; m < 4; ++m)
      av[m] = *reinterpret_cast<const short8*>(&As[(wm*64 + m*16 + lrow)*32 + rchunk]);
    #pragma unroll
    for (int n = 0; n < 4; ++n)
      bv[n] = *reinterpret_cast<const short8*>(&Bs[(wn*64 + n*16 + lrow)*32 + rchunk]);
    #pragma unroll
    for (int m = 0; m < 4; ++m)
      #pragma unroll
      for (int n = 0; n < 4; ++n)
        acc[m][n] = __builtin_amdgcn_mfma_f32_16x16x32_bf16(av[m], bv[n], acc[m][n], 0, 0, 0);
  }

  #pragma unroll
  for (int m = 0; m < 4; ++m) {
    int row0 = rowA0 + wm*64 + m*16 + lk*4;
    #pragma unroll
    for (int n = 0; n < 4; ++n) {
      int col = rowB0 + wn*64 + n*16 + lrow;
      #pragma unroll
      for (int r = 0; r < 4; ++r) {
        float v = acc[m][n][r];
        if constexpr (sizeof(OUT) == 2) C[(size_t)(row0 + r) * N + col] = (OUT)f2bf(v);
        else                            C[(size_t)(row0 + r) * N + col] = v;
      }
    }
  }
}

// ---------------- causal GQA flash attention v4 ----------------
// 1 wave per q-tile (4096 one-wave blocks). Longest-qt blocks dispatch first;
// (b,g) = bid&15 so all blocks sharing a KV stream land on one XCD's L2.
// Ping-pong K/V register prefetch; Q pre-scaled by 0.125*log2e; T13 defer-max;
// T12 permlane32_swap P-pack. ~150 VGPR, no spills (launch_bounds 64,3).
__global__ void __launch_bounds__(64, 3)
k_attn(const unsigned short* __restrict__ Q, const unsigned short* __restrict__ KV,
       const unsigned short* __restrict__ Vt, unsigned short* __restrict__ ctx) {
  const int bid = blockIdx.x;            // 0..4095
  const int c   = bid & 15;              // (b,g) chunk -> fixed XCD
  const int b   = c >> 3, g = c & 7;
  const int within = bid >> 4;           // 0..255
  const int hh  = within & 3;
  const int qt  = 63 - (within >> 2);    // longest first
  const int h   = g*4 + hh;
  const int l   = threadIdx.x;
  const int lq  = l & 31, hi = l >> 5;

  const unsigned short* qp = Q + (size_t)(b*N_ + qt*32 + lq) * DOUT + h*HD_ + hi*8;
  short8 qf0 = *reinterpret_cast<const short8*>(qp);
  short8 qf1 = *reinterpret_cast<const short8*>(qp + 16);
  short8 qf2 = *reinterpret_cast<const short8*>(qp + 32);
  short8 qf3 = *reinterpret_cast<const short8*>(qp + 48);

  const unsigned short* kbase = KV + (size_t)(b*N_ + lq) * 1024 + g*HD_ + hi*8;
  const unsigned short* vbase = Vt + ((size_t)((b*8 + g)*64) + lq) * (size_t)N_ + hi*8;

  f32x16 acc0, acc1;
  #pragma unroll
  for (int r = 0; r < 16; ++r) { acc0[r] = 0.f; acc1[r] = 0.f; }
  float m_run = -3.0e38f, l_run = 0.f;

  short8 k0a, k0b, k0c, k0d, v0a, v0b, v0c, v0d;   // ping
  short8 k1a, k1b, k1c, k1d, v1a, v1b, v1c, v1d;   // pong

  auto loadKV = [&](int t, short8& ka, short8& kb, short8& kc, short8& kd,
                            short8& va, short8& vb, short8& vc, short8& vd) {
    const unsigned short* kp = kbase + (size_t)(t*32) * 1024;
    ka = *reinterpret_cast<const short8*>(kp);
    kb = *reinterpret_cast<const short8*>(kp + 16);
    kc = *reinterpret_cast<const short8*>(kp + 32);
    kd = *reinterpret_cast<const short8*>(kp + 48);
    const unsigned short* vp = vbase + t*32;
    va = *reinterpret_cast<const short8*>(vp);
    vb = *reinterpret_cast<const short8*>(vp + 16);
    vc = *reinterpret_cast<const short8*>(vp + (size_t)32*N_);
    vd = *reinterpret_cast<const short8*>(vp + (size_t)32*N_ + 16);
  };

  auto body = [&](bool diag, short8& ka, short8& kb, short8& kc, short8& kd,
                             short8& va, short8& vb, short8& vc, short8& vd) {
    f32x16 s;
    #pragma unroll
    for (int r = 0; r < 16; ++r) s[r] = 0.f;
    s = __builtin_amdgcn_mfma_f32_32x32x16_bf16(ka, qf0, s, 0, 0, 0);
    s = __builtin_amdgcn_mfma_f32_32x32x16_bf16(kb, qf1, s, 0, 0, 0);
    s = __builtin_amdgcn_mfma_f32_32x32x16_bf16(kc, qf2, s, 0, 0, 0);
    s = __builtin_amdgcn_mfma_f32_32x32x16_bf16(kd, qf3, s, 0, 0, 0);

    if (diag) {
      #pragma unroll
      for (int r = 0; r < 16; ++r) {
        const int ko = (r & 3) + 8*(r >> 2) + 4*hi;
        s[r] = (ko <= lq) ? s[r] : -3.0e38f;
      }
    }
    float t0 = fmaxf(fmaxf(s[0], s[1]), s[2]);
    float t1 = fmaxf(fmaxf(s[3], s[4]), s[5]);
    float t2 = fmaxf(fmaxf(s[6], s[7]), s[8]);
    float t3 = fmaxf(fmaxf(s[9], s[10]), s[11]);
    float t4 = fmaxf(fmaxf(s[12], s[13]), s[14]);
    float mt = fmaxf(fmaxf(fmaxf(t0, t1), fmaxf(t2, t3)), fmaxf(t4, s[15]));
    mt = fmaxf(mt, __shfl_xor(mt, 32));
    if (!__all(mt <= m_run + 8.f)) {          // T13 defer-max
      float nm = fmaxf(m_run, mt);
      float fr = exp2f(m_run - nm);
      m_run = nm;
      l_run *= fr;
      #pragma unroll
      for (int r = 0; r < 16; ++r) { acc0[r] *= fr; acc1[r] *= fr; }
    }
    unsigned int w[8];
    float ps = 0.f;
    #pragma unroll
    for (int i = 0; i < 8; ++i) {
      float p0 = exp2f(s[2*i]   - m_run);
      float p1 = exp2f(s[2*i+1] - m_run);
      ps += p0 + p1;
      asm("v_cvt_pk_bf16_f32 %0, %1, %2" : "=v"(w[i]) : "v"(p0), "v"(p1));
    }
    ps += __shfl_xor(ps, 32);
    l_run += ps;

    // T12: permlane32_swap builds both halves of each P fragment word
    unsigned int x0 = w[0], x1 = w[1], y0 = w[2], y1 = w[3];
    asm("v_permlane32_swap_b32 %0, %1" : "+v"(x0), "+v"(y0));
    asm("v_permlane32_swap_b32 %0, %1" : "+v"(x1), "+v"(y1));
    unsigned int x2 = w[4], x3 = w[5], y2 = w[6], y3 = w[7];
    asm("v_permlane32_swap_b32 %0, %1" : "+v"(x2), "+v"(y2));
    asm("v_permlane32_swap_b32 %0, %1" : "+v"(x3), "+v"(y3));
    int4v p0i, p1i;
    p0i[0] = (int)x0; p0i[1] = (int)x1; p0i[2] = (int)y0; p0i[3] = (int)y1;
    p1i[0] = (int)x2; p1i[1] = (int)x3; p1i[2] = (int)y2; p1i[3] = (int)y3;
    short8 pa0 = __builtin_bit_cast(short8, p0i);
    short8 pa1 = __builtin_bit_cast(short8, p1i);

    acc0 = __builtin_amdgcn_mfma_f32_32x32x16_bf16(va, pa0, acc0, 0, 0, 0);
    acc0 = __builtin_amdgcn_mfma_f32_32x32x16_bf16(vb, pa1, acc0, 0, 0, 0);
    acc1 = __builtin_amdgcn_mfma_f32_32x32x16_bf16(vc, pa0, acc1, 0, 0, 0);
    acc1 = __builtin_amdgcn_mfma_f32_32x32x16_bf16(vd, pa1, acc1, 0, 0, 0);
  };

  loadKV(0, k0a, k0b, k0c, k0d, v0a, v0b, v0c, v0d);
  int t = 0;
  while (true) {
    if (t + 1 <= qt) loadKV(t + 1, k1a, k1b, k1c, k1d, v1a, v1b, v1c, v1d);
    body(t == qt, k0a, k0b, k0c, k0d, v0a, v0b, v0c, v0d);
    if (++t > qt) break;
    if (t + 1 <= qt) loadKV(t + 1, k0a, k0b, k0c, k0d, v0a, v0b, v0c, v0d);
    body(t == qt, k1a, k1b, k1c, k1d, v1a, v1b, v1c, v1d);
    if (++t > qt) break;
  }

  const float rl = 1.f / l_run;
  unsigned short* op = ctx + (size_t)(b*N_ + qt*32 + lq) * DOUT + h*HD_ + 4*hi;
  #pragma unroll
  for (int dt = 0; dt < 2; ++dt) {
    #pragma unroll
    for (int rq = 0; rq < 4; ++rq) {
      const float a0 = (dt ? acc1[4*rq+0] : acc0[4*rq+0]) * rl;
      const float a1 = (dt ? acc1[4*rq+1] : acc0[4*rq+1]) * rl;
      const float a2 = (dt ? acc1[4*rq+2] : acc0[4*rq+2]) * rl;
      const float a3 = (dt ? acc1[4*rq+3] : acc0[4*rq+3]) * rl;
      ushort4 st;
      st.x = f2bf(a0); st.y = f2bf(a1); st.z = f2bf(a2); st.w = f2bf(a3);
      *reinterpret_cast<ushort4*>(op + dt*32 + rq*8) = st;
    }
  }
}

// ---------------- launcher ----------------
extern "C" void kernel_launch(void* const* d_in, const int* in_sizes, int n_in,
                              void* d_out, int out_size, void* d_ws, size_t ws_size,
                              hipStream_t stream) {
  const float* x    = (const float*)d_in[0];
  const float* cosT = (const float*)d_in[1];
  const float* sinT = (const float*)d_in[2];
  const float* Wq   = (const float*)d_in[4];
  const float* Wk   = (const float*)d_in[5];
  const float* Wv   = (const float*)d_in[6];
  const float* Wo   = (const float*)d_in[7];
  float* out = (float*)d_out;

  char* ws = (char*)d_ws;
  unsigned short* xb    = (unsigned short*)(ws);               // 16 MB (reused as ctxb)
  unsigned short* ctxb  = xb;
  unsigned short* Wq_t  = (unsigned short*)(ws + 16777216);    // 8 MB (reused as Vt)
  unsigned short* Vt    = Wq_t;
  unsigned short* Wkv_t = (unsigned short*)(ws + 25165824);    // 4 MB
  unsigned short* Wo_t  = (unsigned short*)(ws + 29360128);    // 8 MB
  unsigned short* Qb    = (unsigned short*)(ws + 37748736);    // 16 MB
  unsigned short* KVb   = (unsigned short*)(ws + 54525952);    // 8 MB

  k_cvt<<<dim3(M_*DIN/4/256), dim3(256), 0, stream>>>(x, xb, M_*DIN/4);

  dim3 tb(32, 8);
  k_transpose<<<dim3(DOUT/32, DIN/32), tb, 0, stream>>>(Wq, Wq_t, DIN, DOUT);
  k_transpose<<<dim3(512/32,  DIN/32), tb, 0, stream>>>(Wk, Wkv_t, DIN, 512);
  k_transpose<<<dim3(512/32,  DIN/32), tb, 0, stream>>>(Wv, Wkv_t + (size_t)512*DIN, DIN, 512);
  k_transpose<<<dim3(DOUT/32, DOUT/32), tb, 0, stream>>>(Wo, Wo_t, DOUT, DOUT);

  k_gemm_bt<unsigned short><<<dim3(DOUT/128, M_/128), 256, 0, stream>>>(xb, Wq_t,  Qb,  M_, DOUT, DIN);
  k_gemm_bt<unsigned short><<<dim3(1024/128, M_/128), 256, 0, stream>>>(xb, Wkv_t, KVb, M_, 1024, DIN);

  const float QSCALE = 0.125f * 1.44269504088896f;   // 1/sqrt(64) * log2(e)
  k_rope<<<dim3(M_*H_*32/256), dim3(256), 0, stream>>>(Qb,  cosT, sinT, H_, DOUT, QSCALE);
  k_rope<<<dim3(M_*G_*32/256), dim3(256), 0, stream>>>(KVb, cosT, sinT, G_, 1024, 1.0f);

  k_vtrans<<<dim3(64, 2, 16), tb, 0, stream>>>(KVb, Vt);

  k_attn<<<dim3(4096), dim3(64), 0, stream>>>(Qb, KVb, Vt, ctxb);

  k_gemm_bt<float><<<dim3(DOUT/128, M_/128), 256, 0, stream>>>(ctxb, Wo_t, out, M_, DOUT, DIN);
}

// Round 5
// 267.569 us; speedup vs baseline: 2.1125x; 1.2418x over previous
//
#include <hip/hip_runtime.h>
#include <hip/hip_bf16.h>
#include <stdint.h>

#define B_   2
#define N_   2048
#define DIN  2048
#define DOUT 2048
#define H_   32
#define G_   8
#define HD_  64
#define M_   (B_*N_)   // 4096

using short8 = __attribute__((ext_vector_type(8))) short;
using f32x4  = __attribute__((ext_vector_type(4))) float;
using f32x16 = __attribute__((ext_vector_type(16))) float;
using int4v  = __attribute__((ext_vector_type(4))) int;

__device__ __forceinline__ unsigned short f2bf(float f) {
  unsigned int u = __float_as_uint(f);
  unsigned int r = u + 0x7FFFu + ((u >> 16) & 1u);
  return (unsigned short)(r >> 16);
}
__device__ __forceinline__ float bf2f(unsigned short h) {
  return __uint_as_float(((unsigned int)h) << 16);
}

// ---------------- elementwise f32 -> bf16 (4 elems/thread) ----------------
__global__ void k_cvt(const float* __restrict__ in, unsigned short* __restrict__ out, int n4) {
  int i = blockIdx.x * 256 + threadIdx.x;
  if (i >= n4) return;
  float4 v = reinterpret_cast<const float4*>(in)[i];
  uint2 o;
  o.x = (unsigned int)f2bf(v.x) | ((unsigned int)f2bf(v.y) << 16);
  o.y = (unsigned int)f2bf(v.z) | ((unsigned int)f2bf(v.w) << 16);
  reinterpret_cast<uint2*>(out)[i] = o;
}

// ---------------- transpose + convert: W (R x C) f32 -> Wt (C x R) bf16 ----------------
__global__ void k_transpose(const float* __restrict__ W, unsigned short* __restrict__ Wt,
                            int R, int C) {
  __shared__ float tile[32][33];
  int c0 = blockIdx.x * 32, r0 = blockIdx.y * 32;
  int tx = threadIdx.x, ty = threadIdx.y;  // (32,8)
  #pragma unroll
  for (int j = 0; j < 4; ++j)
    tile[ty + j*8][tx] = W[(size_t)(r0 + ty + j*8) * C + c0 + tx];
  __syncthreads();
  #pragma unroll
  for (int j = 0; j < 4; ++j)
    Wt[(size_t)(c0 + ty + j*8) * R + r0 + tx] = f2bf(tile[tx][ty + j*8]);
}

// ---------------- bf16 V-transpose: KVb V-half -> Vt[(b*8+g)*64 + d][n] ----------------
__global__ void k_vtrans(const unsigned short* __restrict__ KV, unsigned short* __restrict__ Vt) {
  __shared__ unsigned short tile[32][33];
  int nt = blockIdx.x;   // 0..63 (n tile)
  int dt = blockIdx.y;   // 0..1  (d tile)
  int bg = blockIdx.z;   // 0..15 (b*8+g)
  int b = bg >> 3, g = bg & 7;
  int tx = threadIdx.x, ty = threadIdx.y;  // (32,8)
  const unsigned short* src = KV + (size_t)(b*2048 + nt*32) * 1024 + 512 + g*64 + dt*32;
  #pragma unroll
  for (int j = 0; j < 4; ++j)
    tile[ty + j*8][tx] = src[(size_t)(ty + j*8) * 1024 + tx];   // [n_local][d_local]
  __syncthreads();
  unsigned short* dst = Vt + ((size_t)bg*64 + dt*32) * (size_t)N_ + nt*32;
  #pragma unroll
  for (int j = 0; j < 4; ++j)
    dst[(size_t)(ty + j*8) * N_ + tx] = tile[tx][ty + j*8];     // [d_local][n_local]
}

// ---------------- fragment-linear K/V tile pack ----------------
// Kp/Vp: per (bg, t) a 2048-element (4 KB) tile laid out EXACTLY in load order:
//   element index = chunk*512 + lane*8 + j.
// K chunk c, lane l: K[b][key=t*32+(l&31)][g*64 + c*16 + (l>>5)*8 + j]
// V chunk c, lane l: V^T[d=(c>>1)*32+(l&31)][key=t*32 + (c&1)*16 + (l>>5)*8 + j]
__global__ void __launch_bounds__(64)
k_pack(const unsigned short* __restrict__ KV, const unsigned short* __restrict__ Vt,
       unsigned short* __restrict__ Kp, unsigned short* __restrict__ Vp) {
  const int t  = blockIdx.x;      // 0..63
  const int bg = blockIdx.y;      // 0..15
  const int b = bg >> 3, g = bg & 7;
  const int l = threadIdx.x;
  const int lo = l & 31, hi = l >> 5;
  const size_t base = ((size_t)bg*64 + t) * 2048;
  #pragma unroll
  for (int c = 0; c < 4; ++c) {
    short8 kv = *reinterpret_cast<const short8*>(
        KV + (size_t)(b*2048 + t*32 + lo) * 1024 + g*64 + c*16 + hi*8);
    *reinterpret_cast<short8*>(Kp + base + c*512 + l*8) = kv;
    short8 vv = *reinterpret_cast<const short8*>(
        Vt + ((size_t)bg*64 + (c>>1)*32 + lo) * (size_t)N_ + t*32 + (c&1)*16 + hi*8);
    *reinterpret_cast<short8*>(Vp + base + c*512 + l*8) = vv;
  }
}

// ---------------- in-place RoPE on bf16, optional output scale ----------------
__global__ void k_rope(unsigned short* __restrict__ X, const float* __restrict__ cosT,
                       const float* __restrict__ sinT, int nheads, int rowStride, float scale) {
  int idx = blockIdx.x * 256 + threadIdx.x;
  int dp  = idx & 31;
  int hh  = (idx >> 5) % nheads;
  int row = idx / (32 * nheads);
  if (row >= M_) return;
  int n = row & (N_ - 1);
  float c = cosT[n*HD_ + dp] * scale, s = sinT[n*HD_ + dp] * scale;
  unsigned short* p = X + (size_t)row * rowStride + hh*HD_ + dp;
  float x1 = bf2f(p[0]), x2 = bf2f(p[32]);
  p[0]  = f2bf(x1*c - x2*s);
  p[32] = f2bf(x2*c + x1*s);
}

// ---------------- bf16 GEMM, B given transposed (Bt: N x K row-major) ----------------
template <typename OUT>
__global__ void __launch_bounds__(256)
k_gemm_bt(const unsigned short* __restrict__ A, const unsigned short* __restrict__ Bt,
          OUT* __restrict__ C, int M, int N, int K) {
  __shared__ unsigned short As[128 * 32];
  __shared__ unsigned short Bs[128 * 32];
  const int tid  = threadIdx.x;
  const int wid  = tid >> 6, l = tid & 63;
  const int lrow = l & 15,  lk = l >> 4;
  const int wm = wid >> 1,  wn = wid & 1;
  const int rowA0 = blockIdx.y * 128, rowB0 = blockIdx.x * 128;

  f32x4 acc[4][4];
  #pragma unroll
  for (int m = 0; m < 4; ++m)
    #pragma unroll
    for (int n = 0; n < 4; ++n)
      #pragma unroll
      for (int r = 0; r < 4; ++r) acc[m][n][r] = 0.f;

  int srow[2], scol[2];
  #pragma unroll
  for (int issue = 0; issue < 2; ++issue) {
    int slot = issue*4096 + wid*1024 + l*16;
    int row  = slot >> 6;
    int cp   = (slot >> 4) & 3;
    int sw   = (row & 3) ^ ((row >> 2) & 3);
    srow[issue] = row;
    scol[issue] = (cp ^ sw) * 8;
  }
  const int swr    = (lrow & 3) ^ ((lrow >> 2) & 3);
  const int rchunk = (lk ^ swr) * 8;

  for (int kt = 0; kt < K; kt += 32) {
    __syncthreads();
    #pragma unroll
    for (int issue = 0; issue < 2; ++issue) {
      const unsigned short* ga = A  + (size_t)(rowA0 + srow[issue]) * K + kt + scol[issue];
      const unsigned short* gb = Bt + (size_t)(rowB0 + srow[issue]) * K + kt + scol[issue];
      __builtin_amdgcn_global_load_lds(
          (const __attribute__((address_space(1))) unsigned int*)ga,
          (__attribute__((address_space(3))) unsigned int*)((char*)As + issue*4096 + wid*1024),
          16, 0, 0);
      __builtin_amdgcn_global_load_lds(
          (const __attribute__((address_space(1))) unsigned int*)gb,
          (__attribute__((address_space(3))) unsigned int*)((char*)Bs + issue*4096 + wid*1024),
          16, 0, 0);
    }
    asm volatile("s_waitcnt vmcnt(0)" ::: "memory");
    __syncthreads();

    short8 av[4], bv[4];
    #pragma unroll
    for (int m = 0; m < 4; ++m)
      av[m] = *reinterpret_cast<const short8*>(&As[(wm*64 + m*16 + lrow)*32 + rchunk]);
    #pragma unroll
    for (int n = 0; n < 4; ++n)
      bv[n] = *reinterpret_cast<const short8*>(&Bs[(wn*64 + n*16 + lrow)*32 + rchunk]);
    #pragma unroll
    for (int m = 0; m < 4; ++m)
      #pragma unroll
      for (int n = 0; n < 4; ++n)
        acc[m][n] = __builtin_amdgcn_mfma_f32_16x16x32_bf16(av[m], bv[n], acc[m][n], 0, 0, 0);
  }

  #pragma unroll
  for (int m = 0; m < 4; ++m) {
    int row0 = rowA0 + wm*64 + m*16 + lk*4;
    #pragma unroll
    for (int n = 0; n < 4; ++n) {
      int col = rowB0 + wn*64 + n*16 + lrow;
      #pragma unroll
      for (int r = 0; r < 4; ++r) {
        float v = acc[m][n][r];
        if constexpr (sizeof(OUT) == 2) C[(size_t)(row0 + r) * N + col] = (OUT)f2bf(v);
        else                            C[(size_t)(row0 + r) * N + col] = v;
      }
    }
  }
}

// ---------------- causal GQA flash attention v5 ----------------
// 1 wave per q-tile; fragment-linear Kp/Vp tiles (every load = contiguous 1KB burst).
// Longest-qt first; (b,g)=bid&15 for XCD L2 locality; ping-pong register prefetch;
// Q pre-scaled by 0.125*log2e; T13 defer-max; T12 permlane32_swap P-pack.
__global__ void __launch_bounds__(64, 3)
k_attn(const unsigned short* __restrict__ Q, const unsigned short* __restrict__ Kp,
       const unsigned short* __restrict__ Vp, unsigned short* __restrict__ ctx) {
  const int bid = blockIdx.x;            // 0..4095
  const int c   = bid & 15;              // (b,g) chunk
  const int b   = c >> 3, g = c & 7;
  const int within = bid >> 4;           // 0..255
  const int hh  = within & 3;
  const int qt  = 63 - (within >> 2);    // longest first
  const int h   = g*4 + hh;
  const int l   = threadIdx.x;
  const int lq  = l & 31, hi = l >> 5;

  const unsigned short* qp = Q + (size_t)(b*N_ + qt*32 + lq) * DOUT + h*HD_ + hi*8;
  short8 qf0 = *reinterpret_cast<const short8*>(qp);
  short8 qf1 = *reinterpret_cast<const short8*>(qp + 16);
  short8 qf2 = *reinterpret_cast<const short8*>(qp + 32);
  short8 qf3 = *reinterpret_cast<const short8*>(qp + 48);

  const unsigned short* kpb = Kp + (size_t)c*64*2048 + l*8;
  const unsigned short* vpb = Vp + (size_t)c*64*2048 + l*8;

  f32x16 acc0, acc1;
  #pragma unroll
  for (int r = 0; r < 16; ++r) { acc0[r] = 0.f; acc1[r] = 0.f; }
  float m_run = -3.0e38f, l_run = 0.f;

  short8 k0a, k0b, k0c, k0d, v0a, v0b, v0c, v0d;   // ping
  short8 k1a, k1b, k1c, k1d, v1a, v1b, v1c, v1d;   // pong

  auto loadKV = [&](int t, short8& ka, short8& kb, short8& kc, short8& kd,
                            short8& va, short8& vb, short8& vc, short8& vd) {
    const unsigned short* kp = kpb + (size_t)t*2048;
    ka = *reinterpret_cast<const short8*>(kp);
    kb = *reinterpret_cast<const short8*>(kp + 512);
    kc = *reinterpret_cast<const short8*>(kp + 1024);
    kd = *reinterpret_cast<const short8*>(kp + 1536);
    const unsigned short* vp = vpb + (size_t)t*2048;
    va = *reinterpret_cast<const short8*>(vp);
    vb = *reinterpret_cast<const short8*>(vp + 512);
    vc = *reinterpret_cast<const short8*>(vp + 1024);
    vd = *reinterpret_cast<const short8*>(vp + 1536);
  };

  auto body = [&](bool diag, short8& ka, short8& kb, short8& kc, short8& kd,
                             short8& va, short8& vb, short8& vc, short8& vd) {
    f32x16 s;
    #pragma unroll
    for (int r = 0; r < 16; ++r) s[r] = 0.f;
    s = __builtin_amdgcn_mfma_f32_32x32x16_bf16(ka, qf0, s, 0, 0, 0);
    s = __builtin_amdgcn_mfma_f32_32x32x16_bf16(kb, qf1, s, 0, 0, 0);
    s = __builtin_amdgcn_mfma_f32_32x32x16_bf16(kc, qf2, s, 0, 0, 0);
    s = __builtin_amdgcn_mfma_f32_32x32x16_bf16(kd, qf3, s, 0, 0, 0);

    if (diag) {
      #pragma unroll
      for (int r = 0; r < 16; ++r) {
        const int ko = (r & 3) + 8*(r >> 2) + 4*hi;
        s[r] = (ko <= lq) ? s[r] : -3.0e38f;
      }
    }
    float t0 = fmaxf(fmaxf(s[0], s[1]), s[2]);
    float t1 = fmaxf(fmaxf(s[3], s[4]), s[5]);
    float t2 = fmaxf(fmaxf(s[6], s[7]), s[8]);
    float t3 = fmaxf(fmaxf(s[9], s[10]), s[11]);
    float t4 = fmaxf(fmaxf(s[12], s[13]), s[14]);
    float mt = fmaxf(fmaxf(fmaxf(t0, t1), fmaxf(t2, t3)), fmaxf(t4, s[15]));
    mt = fmaxf(mt, __shfl_xor(mt, 32));
    if (!__all(mt <= m_run + 8.f)) {          // T13 defer-max
      float nm = fmaxf(m_run, mt);
      float fr = exp2f(m_run - nm);
      m_run = nm;
      l_run *= fr;
      #pragma unroll
      for (int r = 0; r < 16; ++r) { acc0[r] *= fr; acc1[r] *= fr; }
    }
    unsigned int w[8];
    float ps = 0.f;
    #pragma unroll
    for (int i = 0; i < 8; ++i) {
      float p0 = exp2f(s[2*i]   - m_run);
      float p1 = exp2f(s[2*i+1] - m_run);
      ps += p0 + p1;
      asm("v_cvt_pk_bf16_f32 %0, %1, %2" : "=v"(w[i]) : "v"(p0), "v"(p1));
    }
    ps += __shfl_xor(ps, 32);
    l_run += ps;

    // T12: permlane32_swap builds both halves of each P fragment word
    unsigned int x0 = w[0], x1 = w[1], y0 = w[2], y1 = w[3];
    asm("v_permlane32_swap_b32 %0, %1" : "+v"(x0), "+v"(y0));
    asm("v_permlane32_swap_b32 %0, %1" : "+v"(x1), "+v"(y1));
    unsigned int x2 = w[4], x3 = w[5], y2 = w[6], y3 = w[7];
    asm("v_permlane32_swap_b32 %0, %1" : "+v"(x2), "+v"(y2));
    asm("v_permlane32_swap_b32 %0, %1" : "+v"(x3), "+v"(y3));
    int4v p0i, p1i;
    p0i[0] = (int)x0; p0i[1] = (int)x1; p0i[2] = (int)y0; p0i[3] = (int)y1;
    p1i[0] = (int)x2; p1i[1] = (int)x3; p1i[2] = (int)y2; p1i[3] = (int)y3;
    short8 pa0 = __builtin_bit_cast(short8, p0i);
    short8 pa1 = __builtin_bit_cast(short8, p1i);

    acc0 = __builtin_amdgcn_mfma_f32_32x32x16_bf16(va, pa0, acc0, 0, 0, 0);
    acc0 = __builtin_amdgcn_mfma_f32_32x32x16_bf16(vb, pa1, acc0, 0, 0, 0);
    acc1 = __builtin_amdgcn_mfma_f32_32x32x16_bf16(vc, pa0, acc1, 0, 0, 0);
    acc1 = __builtin_amdgcn_mfma_f32_32x32x16_bf16(vd, pa1, acc1, 0, 0, 0);
  };

  loadKV(0, k0a, k0b, k0c, k0d, v0a, v0b, v0c, v0d);
  int t = 0;
  while (true) {
    if (t + 1 <= qt) loadKV(t + 1, k1a, k1b, k1c, k1d, v1a, v1b, v1c, v1d);
    body(t == qt, k0a, k0b, k0c, k0d, v0a, v0b, v0c, v0d);
    if (++t > qt) break;
    if (t + 1 <= qt) loadKV(t + 1, k0a, k0b, k0c, k0d, v0a, v0b, v0c, v0d);
    body(t == qt, k1a, k1b, k1c, k1d, v1a, v1b, v1c, v1d);
    if (++t > qt) break;
  }

  const float rl = 1.f / l_run;
  unsigned short* op = ctx + (size_t)(b*N_ + qt*32 + lq) * DOUT + h*HD_ + 4*hi;
  #pragma unroll
  for (int dt = 0; dt < 2; ++dt) {
    #pragma unroll
    for (int rq = 0; rq < 4; ++rq) {
      const float a0 = (dt ? acc1[4*rq+0] : acc0[4*rq+0]) * rl;
      const float a1 = (dt ? acc1[4*rq+1] : acc0[4*rq+1]) * rl;
      const float a2 = (dt ? acc1[4*rq+2] : acc0[4*rq+2]) * rl;
      const float a3 = (dt ? acc1[4*rq+3] : acc0[4*rq+3]) * rl;
      ushort4 st;
      st.x = f2bf(a0); st.y = f2bf(a1); st.z = f2bf(a2); st.w = f2bf(a3);
      *reinterpret_cast<ushort4*>(op + dt*32 + rq*8) = st;
    }
  }
}

// ---------------- launcher ----------------
extern "C" void kernel_launch(void* const* d_in, const int* in_sizes, int n_in,
                              void* d_out, int out_size, void* d_ws, size_t ws_size,
                              hipStream_t stream) {
  const float* x    = (const float*)d_in[0];
  const float* cosT = (const float*)d_in[1];
  const float* sinT = (const float*)d_in[2];
  const float* Wq   = (const float*)d_in[4];
  const float* Wk   = (const float*)d_in[5];
  const float* Wv   = (const float*)d_in[6];
  const float* Wo   = (const float*)d_in[7];
  float* out = (float*)d_out;

  char* ws = (char*)d_ws;
  unsigned short* xb    = (unsigned short*)(ws);               // 16 MB (reused as ctxb)
  unsigned short* ctxb  = xb;
  unsigned short* Wq_t  = (unsigned short*)(ws + 16777216);    // 8 MB; first 4 MB reused as Vt
  unsigned short* Vt    = Wq_t;
  unsigned short* Kp    = (unsigned short*)(ws + 20971520);    // 4 MB (2nd half of Wq_t region)
  unsigned short* Wkv_t = (unsigned short*)(ws + 25165824);    // 4 MB (reused as Vp)
  unsigned short* Vp    = Wkv_t;
  unsigned short* Wo_t  = (unsigned short*)(ws + 29360128);    // 8 MB
  unsigned short* Qb    = (unsigned short*)(ws + 37748736);    // 16 MB
  unsigned short* KVb   = (unsigned short*)(ws + 54525952);    // 8 MB

  k_cvt<<<dim3(M_*DIN/4/256), dim3(256), 0, stream>>>(x, xb, M_*DIN/4);

  dim3 tb(32, 8);
  k_transpose<<<dim3(DOUT/32, DIN/32), tb, 0, stream>>>(Wq, Wq_t, DIN, DOUT);
  k_transpose<<<dim3(512/32,  DIN/32), tb, 0, stream>>>(Wk, Wkv_t, DIN, 512);
  k_transpose<<<dim3(512/32,  DIN/32), tb, 0, stream>>>(Wv, Wkv_t + (size_t)512*DIN, DIN, 512);
  k_transpose<<<dim3(DOUT/32, DOUT/32), tb, 0, stream>>>(Wo, Wo_t, DOUT, DOUT);

  k_gemm_bt<unsigned short><<<dim3(DOUT/128, M_/128), 256, 0, stream>>>(xb, Wq_t,  Qb,  M_, DOUT, DIN);
  k_gemm_bt<unsigned short><<<dim3(1024/128, M_/128), 256, 0, stream>>>(xb, Wkv_t, KVb, M_, 1024, DIN);

  const float QSCALE = 0.125f * 1.44269504088896f;   // 1/sqrt(64) * log2(e)
  k_rope<<<dim3(M_*H_*32/256), dim3(256), 0, stream>>>(Qb,  cosT, sinT, H_, DOUT, QSCALE);
  k_rope<<<dim3(M_*G_*32/256), dim3(256), 0, stream>>>(KVb, cosT, sinT, G_, 1024, 1.0f);

  k_vtrans<<<dim3(64, 2, 16), tb, 0, stream>>>(KVb, Vt);
  k_pack<<<dim3(64, 16), dim3(64), 0, stream>>>(KVb, Vt, Kp, Vp);

  k_attn<<<dim3(4096), dim3(64), 0, stream>>>(Qb, Kp, Vp, ctxb);

  k_gemm_bt<float><<<dim3(DOUT/128, M_/128), 256, 0, stream>>>(ctxb, Wo_t, out, M_, DOUT, DIN);
}